// Round 15
// baseline (46.486 us; speedup 1.0000x reference)
//
#include <hip/hip_runtime.h>
#include <math.h>

// Problem constants (reference: B=4, N=2048, H=5, L=3)
#define B_ 4
#define N_ 2048
#define H_ 5
#define L_ 3
#define EPS_ 1e-6f

constexpr int THREADS = 1024;
constexpr int WAVES = 16;           // 4 waves/SIMD on one CU
constexpr int JPT = N_ / THREADS;   // 2 contiguous elements per thread
constexpr int M_ = 12;              // Taylor terms m = 0..11
constexpr int CHUNKS32 = N_ / 64;   // 32 lane-chunks per row
constexpr float LOG2E = 1.4426950408889634f;

// 1/m! for m=0..11
__device__ __constant__ float INV_FACT[M_] = {
    1.0f, 1.0f, 0.5f, 1.6666666666666666e-01f, 4.1666666666666664e-02f,
    8.3333333333333332e-03f, 1.3888888888888889e-03f, 1.9841269841269841e-04f,
    2.4801587301587302e-05f, 2.7557319223985893e-06f, 2.7557319223985888e-07f,
    2.5052108385441720e-08f};

// Whole 3-layer encoder: ONE dispatch, 4 blocks (one per batch row), ZERO
// inter-block communication. Rank-1 Taylor factorization (see R10):
//   att_i = (sum_m q_i^m/m! T_m - e_ii v_i) / (sum_m q_i^m/m! S_m)
// R14 diagnosis: 4 CUs x 8 waves -> latency-bound weight streams (VALUBusy
// ~20% on active CUs). Fix: 16 waves (2x in-flight loads; waves 0-14 sum one
// head over 1/3 row each -- still ONE butterfly/wave/layer) + row-phase
// weight loads hoisted to layer start so their latency hides under the
// power stream.
__global__ __launch_bounds__(THREADS) void encoder_kernel(
    const float* __restrict__ x,      // [B,N]
    const float* __restrict__ WQ,     // [L,H,N]
    const float* __restrict__ WK,     // [L,H,N]
    const float* __restrict__ WV,     // [L,H,N]
    const float* __restrict__ W0,     // [L,H]
    const float* __restrict__ gamma,  // [N]
    const float* __restrict__ beta,   // [N]
    float* __restrict__ out)          // [B,N]
{
  __shared__ float xb[N_];            // residual row (8 KB)
  __shared__ float STp[WAVES][32];    // per-wave S(0..11)/T(12..23) partials
  __shared__ float fin[H_][32];       // folded S'/T' per head (1/m! applied)
  __shared__ float2 red2[WAVES];      // LN stat partials

  const int b = blockIdx.x;
  const int tid = threadIdx.x;
  const int wave = tid >> 6;
  const int lane = tid & 63;
  const int e0 = tid * JPT;           // 2 contiguous owned elements

  // Power-phase assignment: waves 0-14 -> head = w%5, slice = w/5
  const int phead = wave % H_;
  const int pslice = wave / H_;       // 0,1,2 (wave 15: pslice==3, idle)
  const int c0 = pslice * 11;
  const int c1 = (c0 + 11 < CHUNKS32) ? c0 + 11 : CHUNKS32;

  // Residual slice + LN params in registers for the whole kernel
  float2 xr = *reinterpret_cast<const float2*>(x + b * N_ + e0);
  const float2 gr = *reinterpret_cast<const float2*>(gamma + e0);
  const float2 br = *reinterpret_cast<const float2*>(beta + e0);
  *reinterpret_cast<float2*>(xb + e0) = xr;
  __syncthreads();

  for (int l = 0; l < L_; ++l) {
    // ---- Hoisted row-phase weight loads (latency hides under power) ----
    float2 rq[H_], rk[H_], rv[H_];
#pragma unroll
    for (int h = 0; h < H_; ++h) {
      rq[h] = *reinterpret_cast<const float2*>(WQ + (l * H_ + h) * N_ + e0);
      rk[h] = *reinterpret_cast<const float2*>(WK + (l * H_ + h) * N_ + e0);
      rv[h] = *reinterpret_cast<const float2*>(WV + (l * H_ + h) * N_ + e0);
    }

    // ---- Power phase: wave-private S/T over assigned third of the row ----
    float S[M_], T[M_];
#pragma unroll
    for (int m = 0; m < M_; ++m) { S[m] = 0.f; T[m] = 0.f; }
    if (pslice < 3) {
      const float* wkh = WK + (l * H_ + phead) * N_;
      const float* wvh = WV + (l * H_ + phead) * N_;
#pragma unroll 4
      for (int c = c0; c < c1; ++c) {
        const int j = c * 64 + lane;
        const float xv = xb[j];
        const float k = xv * wkh[j];
        const float v = xv * wvh[j];
        float p = 1.f;
#pragma unroll
        for (int m = 0; m < M_; ++m) {
          S[m] += p;
          T[m] = fmaf(p, v, T[m]);
          p *= k;
        }
      }
      // One 24-value butterfly per wave per layer
#pragma unroll
      for (int m = 0; m < M_; ++m) {
#pragma unroll
        for (int off = 32; off; off >>= 1) {
          S[m] += __shfl_xor(S[m], off);
          T[m] += __shfl_xor(T[m], off);
        }
      }
      if (lane == 0) {
#pragma unroll
        for (int m = 0; m < M_; ++m) {
          STp[wave][m] = S[m];
          STp[wave][12 + m] = T[m];
        }
      }
    }
    __syncthreads();  // B1: STp ready

    // ---- Fold: head h = waves {h, h+5, h+10}; apply 1/m! ----
    if (tid < 160) {
      const int h = tid >> 5, m = tid & 31;
      if (m < 24) {
        float f = STp[h][m] + STp[h + 5][m] + STp[h + 10][m];
        fin[h][m] = f * INV_FACT[m < 12 ? m : m - 12];
      }
    }
    __syncthreads();  // B2: fin ready

    // ---- Row phase: all 5 heads' polynomials on 2 owned elements ----
    float2 asum = make_float2(0.f, 0.f);
#pragma unroll
    for (int h = 0; h < H_; ++h) {
      float Sf[M_], Tf[M_];
#pragma unroll
      for (int m = 0; m < M_; ++m) {
        Sf[m] = fin[h][m];
        Tf[m] = fin[h][12 + m];
      }
      const float w0h = W0[l * H_ + h];
      const float q0 = xr.x * rq[h].x, q1 = xr.y * rq[h].y;
      const float k0 = xr.x * rk[h].x, k1 = xr.y * rk[h].y;
      const float v0 = xr.x * rv[h].x, v1 = xr.y * rv[h].y;
      float d0 = 0.f, n0 = 0.f, pq0 = 1.f;
      float d1 = 0.f, n1 = 0.f, pq1 = 1.f;
#pragma unroll
      for (int m = 0; m < M_; ++m) {
        d0 = fmaf(pq0, Sf[m], d0);
        n0 = fmaf(pq0, Tf[m], n0);
        pq0 *= q0;
        d1 = fmaf(pq1, Sf[m], d1);
        n1 = fmaf(pq1, Tf[m], n1);
        pq1 *= q1;
      }
      const float e0i = __builtin_amdgcn_exp2f(q0 * k0 * LOG2E);
      const float e1i = __builtin_amdgcn_exp2f(q1 * k1 * LOG2E);
      asum.x = fmaf(w0h, (n0 - e0i * v0) * __builtin_amdgcn_rcpf(d0), asum.x);
      asum.y = fmaf(w0h, (n1 - e1i * v1) * __builtin_amdgcn_rcpf(d1), asum.y);
    }

    // ---- Block-local LayerNorm + residual update ----
    float s1 = asum.x + asum.y;
    float s2 = fmaf(asum.x, asum.x, asum.y * asum.y);
#pragma unroll
    for (int off = 32; off; off >>= 1) {
      s1 += __shfl_xor(s1, off);
      s2 += __shfl_xor(s2, off);
    }
    if (lane == 0) red2[wave] = make_float2(s1, s2);
    __syncthreads();  // B3: red2 ready
    s1 = 0.f; s2 = 0.f;
#pragma unroll
    for (int w = 0; w < WAVES; ++w) {
      s1 += red2[w].x;
      s2 += red2[w].y;
    }
    const float mean = s1 * (1.f / N_);
    const float var = (s2 - s1 * mean) * (1.f / (N_ - 1));
    const float inv = 1.f / (sqrtf(var) + EPS_);
    xr.x += gr.x * (asum.x - mean) * inv + br.x;
    xr.y += gr.y * (asum.y - mean) * inv + br.y;

    if (l + 1 < L_) {
      *reinterpret_cast<float2*>(xb + e0) = xr;
      __syncthreads();  // B4: xb ready for next layer's power phase
    }
  }

  // ---- Write final residual (coalesced float2) ----
  *reinterpret_cast<float2*>(out + b * N_ + e0) = xr;
}

extern "C" void kernel_launch(void* const* d_in, const int* in_sizes, int n_in,
                              void* d_out, int out_size, void* d_ws, size_t ws_size,
                              hipStream_t stream) {
  const float* x     = (const float*)d_in[0];
  const float* WQ    = (const float*)d_in[1];
  const float* WK    = (const float*)d_in[2];
  const float* WV    = (const float*)d_in[3];
  const float* W0    = (const float*)d_in[4];
  const float* gamma = (const float*)d_in[5];
  const float* beta  = (const float*)d_in[6];
  float* out = (float*)d_out;

  encoder_kernel<<<B_, THREADS, 0, stream>>>(
      x, WQ, WK, WV, W0, gamma, beta, out);
}

// Round 16
// 44.028 us; speedup vs baseline: 1.0558x; 1.0558x over previous
//
#include <hip/hip_runtime.h>
#include <math.h>

// Problem constants (reference: B=4, N=2048, H=5, L=3)
#define B_ 4
#define N_ 2048
#define H_ 5
#define L_ 3
#define EPS_ 1e-6f

constexpr int THREADS = 512;
constexpr int WAVES = 8;            // 2 waves/SIMD on the one CU per block
constexpr int JPT = N_ / THREADS;   // 4 contiguous elements per thread
constexpr int M_ = 12;              // Taylor terms m = 0..11
constexpr float LOG2E = 1.4426950408889634f;

// 1/m! for m=0..11
__device__ __constant__ float INV_FACT[M_] = {
    1.0f, 1.0f, 0.5f, 1.6666666666666666e-01f, 4.1666666666666664e-02f,
    8.3333333333333332e-03f, 1.3888888888888889e-03f, 1.9841269841269841e-04f,
    2.4801587301587302e-05f, 2.7557319223985893e-06f, 2.7557319223985888e-07f,
    2.5052108385441720e-08f};

// Whole 3-layer encoder: ONE dispatch, 4 blocks (one per batch row), ZERO
// inter-block communication. Rank-1 Taylor factorization (see R10):
//   att_i = (sum_m q_i^m/m! T_m - e_ii v_i) / (sum_m q_i^m/m! S_m)
// R14 structure (one butterfly/wave/layer, 4 barriers/layer) + R16 change:
// BATCHED loads. Each wave issues its entire power-phase wk/wv slice
// (<=16 float4 loads, independent) BEFORE any compute, and the row-phase
// wq/wk/wv float4s are issued in the same shadow -> HBM latency is covered
// by the issue stream instead of serializing per 4-chunk unroll (R14's
// ~80%-stall diagnosis).
__global__ __launch_bounds__(THREADS) void encoder_kernel(
    const float* __restrict__ x,      // [B,N]
    const float* __restrict__ WQ,     // [L,H,N]
    const float* __restrict__ WK,     // [L,H,N]
    const float* __restrict__ WV,     // [L,H,N]
    const float* __restrict__ W0,     // [L,H]
    const float* __restrict__ gamma,  // [N]
    const float* __restrict__ beta,   // [N]
    float* __restrict__ out)          // [B,N]
{
  __shared__ float xb[N_];            // residual row (8 KB)
  __shared__ float STp[WAVES][32];    // per-wave S(0..11)/T(12..23) partials
  __shared__ float fin[H_][32];       // folded S'/T' per head (1/m! applied)
  __shared__ float2 red2[WAVES];      // LN stat partials

  const int b = blockIdx.x;
  const int tid = threadIdx.x;
  const int wave = tid >> 6;
  const int lane = tid & 63;
  const int e0 = tid * JPT;           // 4 contiguous owned elements

  // Power-phase wave->head assignment (R14): heads 0-2 get two waves
  // (half row each), heads 3-4 one wave (full row).
  const int phead = (wave < 5) ? wave : wave - 5;
  const int pbase = (wave < 5) ? 0 : 1024;
  const int nit = (phead < 3) ? 4 : 8;    // float4 iterations per lane

  // Residual slice + LN params in registers for the whole kernel
  float xr[JPT], gr[JPT], br[JPT];
  {
    float4 t = *reinterpret_cast<const float4*>(x + b * N_ + e0);
    xr[0] = t.x; xr[1] = t.y; xr[2] = t.z; xr[3] = t.w;
    t = *reinterpret_cast<const float4*>(gamma + e0);
    gr[0] = t.x; gr[1] = t.y; gr[2] = t.z; gr[3] = t.w;
    t = *reinterpret_cast<const float4*>(beta + e0);
    br[0] = t.x; br[1] = t.y; br[2] = t.z; br[3] = t.w;
  }
  *reinterpret_cast<float4*>(xb + e0) =
      make_float4(xr[0], xr[1], xr[2], xr[3]);
  __syncthreads();

  for (int l = 0; l < L_; ++l) {
    const float* wkh = WK + (l * H_ + phead) * N_ + pbase;
    const float* wvh = WV + (l * H_ + phead) * N_ + pbase;

    // ---- BATCH-ISSUE all power-phase weight loads (independent) ----
    float4 bk[8], bv[8];
    if (nit == 4) {
#pragma unroll
      for (int i = 0; i < 4; ++i) {
        bk[i] = *reinterpret_cast<const float4*>(wkh + i * 256 + lane * 4);
        bv[i] = *reinterpret_cast<const float4*>(wvh + i * 256 + lane * 4);
      }
    } else {
#pragma unroll
      for (int i = 0; i < 8; ++i) {
        bk[i] = *reinterpret_cast<const float4*>(wkh + i * 256 + lane * 4);
        bv[i] = *reinterpret_cast<const float4*>(wvh + i * 256 + lane * 4);
      }
    }

    // ---- Issue row-phase weight loads in the same latency shadow ----
    float4 rq[H_], rk[H_], rv[H_];
#pragma unroll
    for (int h = 0; h < H_; ++h) {
      rq[h] = *reinterpret_cast<const float4*>(WQ + (l * H_ + h) * N_ + e0);
      rk[h] = *reinterpret_cast<const float4*>(WK + (l * H_ + h) * N_ + e0);
      rv[h] = *reinterpret_cast<const float4*>(WV + (l * H_ + h) * N_ + e0);
    }

    // ---- Power phase: wave-private S/T from batched registers ----
    float S[M_], T[M_];
#pragma unroll
    for (int m = 0; m < M_; ++m) { S[m] = 0.f; T[m] = 0.f; }
#pragma unroll 2
    for (int i = 0; i < nit; ++i) {
      float4 xv4 =
          *reinterpret_cast<const float4*>(xb + pbase + i * 256 + lane * 4);
      const float xa[4] = {xv4.x, xv4.y, xv4.z, xv4.w};
      const float ka[4] = {bk[i].x, bk[i].y, bk[i].z, bk[i].w};
      const float va[4] = {bv[i].x, bv[i].y, bv[i].z, bv[i].w};
#pragma unroll
      for (int u = 0; u < 4; ++u) {
        const float k = xa[u] * ka[u];
        const float v = xa[u] * va[u];
        float p = 1.f;
#pragma unroll
        for (int m = 0; m < M_; ++m) {
          S[m] += p;
          T[m] = fmaf(p, v, T[m]);
          p *= k;
        }
      }
    }

    // One 24-value butterfly per wave per layer
#pragma unroll
    for (int m = 0; m < M_; ++m) {
#pragma unroll
      for (int off = 32; off; off >>= 1) {
        S[m] += __shfl_xor(S[m], off);
        T[m] += __shfl_xor(T[m], off);
      }
    }
    if (lane == 0) {
#pragma unroll
      for (int m = 0; m < M_; ++m) {
        STp[wave][m] = S[m];
        STp[wave][12 + m] = T[m];
      }
    }
    __syncthreads();  // B1: STp ready

    // ---- Fold: head h<3 = waves {h, h+5}; h>=3 = wave h; apply 1/m! ----
    if (tid < 160) {
      const int h = tid >> 5, m = tid & 31;
      if (m < 24) {
        float f = STp[h][m];
        if (h < 3) f += STp[h + 5][m];
        fin[h][m] = f * INV_FACT[m < 12 ? m : m - 12];
      }
    }
    __syncthreads();  // B2: fin ready

    // ---- Row phase: all 5 heads' polynomials on 4 owned elements ----
    float asum[JPT] = {0.f, 0.f, 0.f, 0.f};
#pragma unroll
    for (int h = 0; h < H_; ++h) {
      float Sf[M_], Tf[M_];
#pragma unroll
      for (int m = 0; m < M_; ++m) {
        Sf[m] = fin[h][m];
        Tf[m] = fin[h][12 + m];
      }
      const float wqa[4] = {rq[h].x, rq[h].y, rq[h].z, rq[h].w};
      const float wka[4] = {rk[h].x, rk[h].y, rk[h].z, rk[h].w};
      const float wva[4] = {rv[h].x, rv[h].y, rv[h].z, rv[h].w};
      const float w0h = W0[l * H_ + h];
#pragma unroll
      for (int u = 0; u < JPT; ++u) {
        const float q = xr[u] * wqa[u];
        const float k = xr[u] * wka[u];
        const float v = xr[u] * wva[u];
        float d = 0.f, n = 0.f, pq = 1.f;
#pragma unroll
        for (int m = 0; m < M_; ++m) {
          d = fmaf(pq, Sf[m], d);
          n = fmaf(pq, Tf[m], n);
          pq *= q;
        }
        const float eii = __builtin_amdgcn_exp2f(q * k * LOG2E);
        asum[u] = fmaf(w0h, (n - eii * v) * __builtin_amdgcn_rcpf(d), asum[u]);
      }
    }

    // ---- Block-local LayerNorm + residual update ----
    float s1 = 0.f, s2 = 0.f;
#pragma unroll
    for (int u = 0; u < JPT; ++u) {
      s1 += asum[u];
      s2 = fmaf(asum[u], asum[u], s2);
    }
#pragma unroll
    for (int off = 32; off; off >>= 1) {
      s1 += __shfl_xor(s1, off);
      s2 += __shfl_xor(s2, off);
    }
    if (lane == 0) red2[wave] = make_float2(s1, s2);
    __syncthreads();  // B3: red2 ready
    s1 = 0.f; s2 = 0.f;
#pragma unroll
    for (int w = 0; w < WAVES; ++w) {
      s1 += red2[w].x;
      s2 += red2[w].y;
    }
    const float mean = s1 * (1.f / N_);
    const float var = (s2 - s1 * mean) * (1.f / (N_ - 1));
    const float inv = 1.f / (sqrtf(var) + EPS_);
#pragma unroll
    for (int u = 0; u < JPT; ++u) {
      xr[u] += gr[u] * (asum[u] - mean) * inv + br[u];
    }

    if (l + 1 < L_) {
      *reinterpret_cast<float4*>(xb + e0) =
          make_float4(xr[0], xr[1], xr[2], xr[3]);
      __syncthreads();  // B4: xb ready for next layer's power phase
    }
  }

  // ---- Write final residual (coalesced float4) ----
  *reinterpret_cast<float4*>(out + b * N_ + e0) =
      make_float4(xr[0], xr[1], xr[2], xr[3]);
}

extern "C" void kernel_launch(void* const* d_in, const int* in_sizes, int n_in,
                              void* d_out, int out_size, void* d_ws, size_t ws_size,
                              hipStream_t stream) {
  const float* x     = (const float*)d_in[0];
  const float* WQ    = (const float*)d_in[1];
  const float* WK    = (const float*)d_in[2];
  const float* WV    = (const float*)d_in[3];
  const float* W0    = (const float*)d_in[4];
  const float* gamma = (const float*)d_in[5];
  const float* beta  = (const float*)d_in[6];
  float* out = (float*)d_out;

  encoder_kernel<<<B_, THREADS, 0, stream>>>(
      x, WQ, WK, WV, W0, gamma, beta, out);
}